// Round 2
// baseline (774.760 us; speedup 1.0000x reference)
//
#include <hip/hip_runtime.h>
#include <hip/hip_bf16.h>

#define S_LEN 2048
#define BATCH 64
#define DMODEL 512
#define NHEAD 8
#define HDIM 64
#define LN_EPS_F 1e-5f
#define QSCALE 0.125f  // 1/sqrt(64)

// ---------------------------------------------------------------------------
// K1: q[b,:] = (src[last_b, b, :] @ Wq^T + bq) * scale ; qk[b,h,:] = Wk_h^T q_bh
// grid: B blocks, 256 threads
// ---------------------------------------------------------------------------
__global__ void __launch_bounds__(256) k_q_qk(
    const float* __restrict__ src, const int* __restrict__ seqlen,
    const float* __restrict__ w_in, const float* __restrict__ b_in,
    float* __restrict__ qk)
{
    __shared__ float xl[DMODEL];
    __shared__ float ql[DMODEL];
    const int b = blockIdx.x;
    const int t = threadIdx.x;
    const int last = seqlen[b] - 1;
    const float* xrow = src + ((size_t)last * BATCH + b) * DMODEL;
    for (int i = t; i < DMODEL; i += 256) xl[i] = xrow[i];
    __syncthreads();
    // q (kept in LDS, pre-scaled)
    for (int d = t; d < DMODEL; d += 256) {
        const float* wr = w_in + (size_t)d * DMODEL;
        float acc = b_in[d];
        for (int i = 0; i < DMODEL; i += 4) {
            const float4 r = *reinterpret_cast<const float4*>(wr + i);
            acc += r.x * xl[i] + r.y * xl[i + 1] + r.z * xl[i + 2] + r.w * xl[i + 3];
        }
        ql[d] = acc * QSCALE;
    }
    __syncthreads();
    // qk[b][h][dp] = sum_j Wk[h*64+j][dp] * ql[h*64+j]   (bk drops out of softmax)
    for (int h = 0; h < NHEAD; h++) {
        for (int dp = t; dp < DMODEL; dp += 256) {
            float acc = 0.f;
#pragma unroll 8
            for (int j = 0; j < HDIM; j++) {
                acc += w_in[((size_t)(DMODEL + h * HDIM + j)) * DMODEL + dp] * ql[h * HDIM + j];
            }
            qk[((size_t)b * NHEAD + h) * DMODEL + dp] = acc;
        }
    }
}

// ---------------------------------------------------------------------------
// K2: scores[b,h,s] = qk[b,h,:] . src[s,b,:]
// grid: (B, S/32), 256 threads = 4 waves, each wave does 8 s-values
// qk fragment lives in registers (64 VGPRs), x loaded as 2x float4 per lane.
// ---------------------------------------------------------------------------
__global__ void __launch_bounds__(256) k_scores(
    const float* __restrict__ src, const float* __restrict__ qk,
    float* __restrict__ scores)
{
    const int b = blockIdx.x;
    const int sb = blockIdx.y;
    const int t = threadIdx.x;
    const int wave = t >> 6, lane = t & 63;

    float qr[NHEAD][8];
    const float* qb = qk + (size_t)b * NHEAD * DMODEL;
#pragma unroll
    for (int h = 0; h < NHEAD; h++) {
        const float4 a = *reinterpret_cast<const float4*>(qb + h * DMODEL + lane * 8);
        const float4 c = *reinterpret_cast<const float4*>(qb + h * DMODEL + lane * 8 + 4);
        qr[h][0] = a.x; qr[h][1] = a.y; qr[h][2] = a.z; qr[h][3] = a.w;
        qr[h][4] = c.x; qr[h][5] = c.y; qr[h][6] = c.z; qr[h][7] = c.w;
    }
#pragma unroll
    for (int i = 0; i < 8; i++) {
        const int s = sb * 32 + wave * 8 + i;
        const float* xrow = src + ((size_t)s * BATCH + b) * DMODEL + lane * 8;
        const float4 xa = *reinterpret_cast<const float4*>(xrow);
        const float4 xc = *reinterpret_cast<const float4*>(xrow + 4);
        float xf[8];
        xf[0] = xa.x; xf[1] = xa.y; xf[2] = xa.z; xf[3] = xa.w;
        xf[4] = xc.x; xf[5] = xc.y; xf[6] = xc.z; xf[7] = xc.w;
        float p[NHEAD];
#pragma unroll
        for (int h = 0; h < NHEAD; h++) {
            float a = 0.f;
#pragma unroll
            for (int j = 0; j < 8; j++) a += qr[h][j] * xf[j];
            p[h] = a;
        }
#pragma unroll
        for (int off = 32; off; off >>= 1) {
#pragma unroll
            for (int h = 0; h < NHEAD; h++) p[h] += __shfl_down(p[h], off, 64);
        }
        if (lane == 0) {
#pragma unroll
            for (int h = 0; h < NHEAD; h++)
                scores[((size_t)b * NHEAD + h) * S_LEN + s] = p[h];
        }
    }
}

// ---------------------------------------------------------------------------
// K3: softmax over s for each (b,h). grid: B*H blocks, 256 threads, 8 vals/thread
// ---------------------------------------------------------------------------
__global__ void __launch_bounds__(256) k_softmax(float* __restrict__ scores)
{
    const int bh = blockIdx.x;
    const int t = threadIdx.x;
    float* p = scores + (size_t)bh * S_LEN;
    float v[8];
    float m = -1e30f;
#pragma unroll
    for (int k = 0; k < 8; k++) { v[k] = p[t + k * 256]; m = fmaxf(m, v[k]); }
    __shared__ float red[256];
    red[t] = m; __syncthreads();
    for (int o = 128; o; o >>= 1) { if (t < o) red[t] = fmaxf(red[t], red[t + o]); __syncthreads(); }
    m = red[0];
    __syncthreads();
    float s = 0.f;
#pragma unroll
    for (int k = 0; k < 8; k++) { v[k] = __expf(v[k] - m); s += v[k]; }
    red[t] = s; __syncthreads();
    for (int o = 128; o; o >>= 1) { if (t < o) red[t] += red[t + o]; __syncthreads(); }
    const float inv = 1.0f / red[0];
#pragma unroll
    for (int k = 0; k < 8; k++) p[t + k * 256] = v[k] * inv;
}

// ---------------------------------------------------------------------------
// K4: xbar partials: xpart[c][b][h][d] = sum_{s in chunk c} attn[b,h,s]*src[s,b,d]
// grid: (B, 8 chunks of 256 s), 256 threads; thread owns d=2t,2t+1
// ---------------------------------------------------------------------------
__global__ void __launch_bounds__(256) k_xbar(
    const float* __restrict__ src, const float* __restrict__ attn,
    float* __restrict__ xpart)
{
    __shared__ float al[NHEAD][256];
    const int b = blockIdx.x;
    const int c = blockIdx.y;
    const int t = threadIdx.x;
    const int s0 = c * 256;
#pragma unroll
    for (int h = 0; h < NHEAD; h++)
        al[h][t] = attn[((size_t)b * NHEAD + h) * S_LEN + s0 + t];
    __syncthreads();
    float acc0[NHEAD] = {0.f, 0.f, 0.f, 0.f, 0.f, 0.f, 0.f, 0.f};
    float acc1[NHEAD] = {0.f, 0.f, 0.f, 0.f, 0.f, 0.f, 0.f, 0.f};
    const float* base = src + (size_t)s0 * BATCH * DMODEL + (size_t)b * DMODEL + 2 * t;
#pragma unroll 4
    for (int i = 0; i < 256; i++) {
        const float2 xv = *reinterpret_cast<const float2*>(base + (size_t)i * BATCH * DMODEL);
#pragma unroll
        for (int h = 0; h < NHEAD; h++) {
            const float a = al[h][i];
            acc0[h] += a * xv.x;
            acc1[h] += a * xv.y;
        }
    }
#pragma unroll
    for (int h = 0; h < NHEAD; h++) {
        const size_t idx = (((size_t)c * BATCH + b) * NHEAD + h) * DMODEL + 2 * t;
        *reinterpret_cast<float2*>(xpart + idx) = make_float2(acc0[h], acc1[h]);
    }
}

// ---------------------------------------------------------------------------
// K5: reduce partials -> ctx = Wv . xbar + bv -> attn_out = ctx . Wout^T + bout
// grid: B blocks, 256 threads
// ---------------------------------------------------------------------------
__global__ void __launch_bounds__(256) k_ctx_proj(
    const float* __restrict__ xpart, const float* __restrict__ w_in,
    const float* __restrict__ b_in, const float* __restrict__ w_out,
    const float* __restrict__ b_out, float* __restrict__ attn_out)
{
    __shared__ float xb[NHEAD * DMODEL];  // 16 KB
    __shared__ float ctx[DMODEL];
    const int b = blockIdx.x;
    const int t = threadIdx.x;
    for (int i = t; i < NHEAD * DMODEL; i += 256) {
        float a = 0.f;
#pragma unroll
        for (int c = 0; c < 8; c++)
            a += xpart[(((size_t)c * BATCH + b) * NHEAD) * DMODEL + i];
        xb[i] = a;
    }
    __syncthreads();
    for (int e = t; e < DMODEL; e += 256) {
        const int h = e >> 6;
        const float* wr = w_in + ((size_t)(2 * DMODEL + e)) * DMODEL;
        float acc = b_in[2 * DMODEL + e];
        const float* xr = &xb[h * DMODEL];
        for (int d = 0; d < DMODEL; d += 4) {
            const float4 r = *reinterpret_cast<const float4*>(wr + d);
            acc += r.x * xr[d] + r.y * xr[d + 1] + r.z * xr[d + 2] + r.w * xr[d + 3];
        }
        ctx[e] = acc;
    }
    __syncthreads();
    for (int o = t; o < DMODEL; o += 256) {
        const float* wr = w_out + (size_t)o * DMODEL;
        float acc = b_out[o];
        for (int e = 0; e < DMODEL; e += 4) {
            const float4 r = *reinterpret_cast<const float4*>(wr + e);
            acc += r.x * ctx[e] + r.y * ctx[e + 1] + r.z * ctx[e + 2] + r.w * ctx[e + 3];
        }
        attn_out[(size_t)b * DMODEL + o] = acc;
    }
}

// ---------------------------------------------------------------------------
// K6: out[s,b,:] = LayerNorm(src[s,b,:] + attn_out[b,:]) * g + beta
// grid: S*B blocks (one row each), 256 threads; thread owns d=2t,2t+1
// ---------------------------------------------------------------------------
__global__ void __launch_bounds__(256) k_ln(
    const float* __restrict__ src, const float* __restrict__ attn_out,
    const float* __restrict__ g, const float* __restrict__ beta,
    float* __restrict__ out)
{
    const int row = blockIdx.x;  // s*BATCH + b
    const int b = row & (BATCH - 1);
    const int t = threadIdx.x;
    const float2 xv = *(reinterpret_cast<const float2*>(src + (size_t)row * DMODEL) + t);
    const float2 ao = *reinterpret_cast<const float2*>(attn_out + (size_t)b * DMODEL + 2 * t);
    const float x0 = xv.x + ao.x;
    const float x1 = xv.y + ao.y;
    __shared__ float rs[256], rq[256];
    rs[t] = x0 + x1;
    rq[t] = x0 * x0 + x1 * x1;
    __syncthreads();
    for (int o = 128; o; o >>= 1) {
        if (t < o) { rs[t] += rs[t + o]; rq[t] += rq[t + o]; }
        __syncthreads();
    }
    const float mu = rs[0] * (1.0f / DMODEL);
    const float var = rq[0] * (1.0f / DMODEL) - mu * mu;
    const float inv = rsqrtf(var + LN_EPS_F);
    const float y0 = (x0 - mu) * inv * g[2 * t] + beta[2 * t];
    const float y1 = (x1 - mu) * inv * g[2 * t + 1] + beta[2 * t + 1];
    *reinterpret_cast<float2*>(out + (size_t)row * DMODEL + 2 * t) = make_float2(y0, y1);
}

extern "C" void kernel_launch(void* const* d_in, const int* in_sizes, int n_in,
                              void* d_out, int out_size, void* d_ws, size_t ws_size,
                              hipStream_t stream)
{
    const float* src   = (const float*)d_in[0];
    const int*   slen  = (const int*)d_in[1];
    const float* w_in  = (const float*)d_in[2];
    const float* b_in  = (const float*)d_in[3];
    const float* w_out = (const float*)d_in[4];
    const float* b_out = (const float*)d_in[5];
    const float* g     = (const float*)d_in[6];
    const float* beta  = (const float*)d_in[7];
    float* out = (float*)d_out;

    char* ws = (char*)d_ws;
    float* qk       = (float*)(ws);                      // B*H*D   = 1 MB
    float* scores   = (float*)(ws + (1u << 20));         // B*H*S   = 4 MB
    float* xpart    = (float*)(ws + 5u * (1u << 20));    // 8*B*H*D = 8 MB
    float* attn_out = (float*)(ws + 13u * (1u << 20));   // B*D     = 128 KB

    k_q_qk<<<BATCH, 256, 0, stream>>>(src, slen, w_in, b_in, qk);
    k_scores<<<dim3(BATCH, S_LEN / 32), 256, 0, stream>>>(src, qk, scores);
    k_softmax<<<BATCH * NHEAD, 256, 0, stream>>>(scores);
    k_xbar<<<dim3(BATCH, 8), 256, 0, stream>>>(src, scores, xpart);
    k_ctx_proj<<<BATCH, 256, 0, stream>>>(xpart, w_in, b_in, w_out, b_out, attn_out);
    k_ln<<<S_LEN * BATCH, 256, 0, stream>>>(src, attn_out, g, beta, out);
}